// Round 2
// baseline (1079.616 us; speedup 1.0000x reference)
//
#include <hip/hip_runtime.h>

#define NEGF (-1e30f)

typedef __attribute__((ext_vector_type(8))) short short8;
typedef __attribute__((ext_vector_type(4))) float float4v;

template <bool V> struct BC { static constexpr bool value = V; };

__device__ __forceinline__ short f2bf(float f) {
  union { float f; unsigned u; } v; v.f = f;
  unsigned r = v.u + 0x7fffu + ((v.u >> 16) & 1u);  // RNE truncate to bf16
  return (short)(r >> 16);
}
__device__ __forceinline__ float fastrcp(float x) { return __builtin_amdgcn_rcpf(x); }
__device__ __forceinline__ float clamp15(float x) { return fminf(15.0f, fmaxf(-15.0f, x)); }

// ---------------------------------------------------------------------------
// prep: stage Wcat = [Wh1;Wh2] (256x640 f32) into bf16 MFMA B-fragment layout.
__global__ void prep_w_kernel(const float* __restrict__ Wh1, const float* __restrict__ Wh2,
                              short* __restrict__ wsW) {
  int t = blockIdx.x * 256 + threadIdx.x;   // 0..20479
  int lane = t & 63;
  int frag = t >> 6;                        // 0..319
  int nt = frag >> 3, kk = frag & 7;
  int n  = nt * 16 + (lane & 15);
  int kb = kk * 32 + (lane >> 4) * 8;
  short8 v;
#pragma unroll
  for (int j = 0; j < 8; ++j) {
    int k = kb + j;
    float w = (k < 128) ? Wh1[k * 640 + n] : Wh2[(k - 128) * 640 + n];
    v[j] = f2bf(w);
  }
  ((short8*)wsW)[frag * 64 + lane] = v;
}

// ---------------------------------------------------------------------------
// MDLSTM wavefront, ONE block per batch (32 blocks x 512 threads).
// All 32 rows in one workgroup: row-boundary h/c exchange is LDS+barrier
// (was cross-block device atomics + cross-XCD flag ping-pong). Each wave g
// owns output columns jj=g*16..+15 for BOTH row-halves (B-fragments shared:
// one load, two MFMAs). feat: 33-slot LDS ring (flushed slot provably
// disjoint from the 32 written per step), one coalesced store per column.
// LDS total 150,064 B (< proven 156,704). No atomics, no flags, no spins.
__global__ __launch_bounds__(512)
void mdlstm_kernel(const float* __restrict__ X, const short* __restrict__ wsW,
                   const float* __restrict__ Wx, const float* __restrict__ bias,
                   float* __restrict__ feat) {
  __shared__ __align__(16) short h_buf[2][33][136];   // 17,952 B; row 0 = zero boundary
  __shared__ __align__(16) short wlds[14 * 4096];     // 114,688 B: g3 kk0-6, g4 kk0-6
  __shared__ float featbuf[33][132];                  // 17,424 B: ring (pad 132: quad-spread banks)

  const int bat  = blockIdx.x;
  const int tid  = threadIdx.x;
  const int lane = tid & 63;
  const int g    = tid >> 6;          // 0..7: output column slice
  const int col  = lane & 15;
  const int quad = lane >> 4;
  const int jj   = g * 16 + col;

  for (int i = tid; i < 4488; i += 512) ((int*)h_buf)[i] = 0;
  for (int i = tid; i < 33 * 132; i += 512) ((float*)featbuf)[i] = 0.0f;
  {
    const uint4* s4 = (const uint4*)wsW;
    uint4* d4 = (uint4*)wlds;
    for (int i = tid; i < 14 * 512; i += 512) {
      int c = i >> 9, off = i & 511;                  // chunk c, off = gg*64+ln
      int gg = off >> 6, ln = off & 63;
      int q  = (c < 7) ? 3 : 4;
      int kk = (c < 7) ? c : (c - 7);
      d4[i] = s4[(((q * 8 + gg) * 8) + kk) * 64 + ln];
    }
  }

  float wx[5], bg[5];
#pragma unroll
  for (int q = 0; q < 5; ++q) {
    wx[q] = Wx[q * 128 + jj];
    bg[q] = bias[q * 128 + jj];
  }

  // Loop-invariant B-fragments in registers: gates 0,1,2 all kk (96 VGPR)
  // plus gate3 kk=7 and gate4 kk=7 (8 VGPR). No per-step global weight loads.
  const short8* W8 = (const short8*)wsW;
  short8 rb0[8], rb1[8], rb2[8];
#pragma unroll
  for (int kk = 0; kk < 8; ++kk) {
    rb0[kk] = W8[((0 * 8 + g) * 8 + kk) * 64 + lane];
    rb1[kk] = W8[((1 * 8 + g) * 8 + kk) * 64 + lane];
    rb2[kk] = W8[((2 * 8 + g) * 8 + kk) * 64 + lane];
  }
  const short8 rb37 = W8[((3 * 8 + g) * 8 + 7) * 64 + lane];
  const short8 rb47 = W8[((4 * 8 + g) * 8 + 7) * 64 + lane];

  const short8* pL3 = (const short8*)wlds + g * 64 + lane;             // chunk kk   (kk<7)
  const short8* pL4 = (const short8*)wlds + 7 * 512 + g * 64 + lane;   // chunk 7+kk (kk<7)

  float cp0[4] = {0.f, 0.f, 0.f, 0.f};   // c-state rows quad*4+r      (half0)
  float cp1[4] = {0.f, 0.f, 0.f, 0.f};   // c-state rows 16+quad*4+r   (half1)
  const float* Xb = X + bat * 8192;      // X[b][t=256][f=32]
  float* fb = feat + bat * 32768;        // feat[b][w=256][jj=128]

  int sb = 0;                            // d % 33
  __syncthreads();

  auto stepT = [&](int d, auto allv_) {
    constexpr bool ALLV = decltype(allv_)::value;
    const int rbuf = (d + 1) & 1, wbuf = d & 1;

    // Flush column w=d-32 (complete at end of step d-1). Its slot (d+1)%33
    // is written by NO thread during step d (writers cover the other 32
    // slots) and next written only after this step's barrier -> race-free.
    if (d >= 32 && tid < 128) {
      int fs = sb + 1; if (fs >= 33) fs = 0;
      float v = featbuf[fs][tid];
      featbuf[fs][tid] = 0.0f;
      fb[(d - 32) * 128 + tid] = v;       // fire-and-forget; ack hides under compute
    }

    float4v acc0[5], acc1[5];
#pragma unroll
    for (int q = 0; q < 5; ++q) {
      acc0[q] = (float4v){bg[q], bg[q], bg[q], bg[q]};
      acc1[q] = acc0[q];
    }
#pragma unroll
    for (int kk = 0; kk < 8; ++kk) {
      const int up = kk >> 2;                       // kk<4: h_left; else h_up
      const int ccc = (kk & 3) * 32 + quad * 8;
      short8 a0 = *(const short8*)&h_buf[rbuf][col + 1 - up][ccc];   // rows 0..15
      short8 a1 = *(const short8*)&h_buf[rbuf][17 + col - up][ccc];  // rows 16..31
      short8 b3 = (kk < 7) ? pL3[kk * 512] : rb37;
      acc0[3] = __builtin_amdgcn_mfma_f32_16x16x32_bf16(a0, b3, acc0[3], 0, 0, 0);
      acc1[3] = __builtin_amdgcn_mfma_f32_16x16x32_bf16(a1, b3, acc1[3], 0, 0, 0);
      short8 b4 = (kk < 7) ? pL4[kk * 512] : rb47;
      acc0[4] = __builtin_amdgcn_mfma_f32_16x16x32_bf16(a0, b4, acc0[4], 0, 0, 0);
      acc1[4] = __builtin_amdgcn_mfma_f32_16x16x32_bf16(a1, b4, acc1[4], 0, 0, 0);
      short8 b0 = rb0[kk];
      acc0[0] = __builtin_amdgcn_mfma_f32_16x16x32_bf16(a0, b0, acc0[0], 0, 0, 0);
      acc1[0] = __builtin_amdgcn_mfma_f32_16x16x32_bf16(a1, b0, acc1[0], 0, 0, 0);
      short8 b1 = rb1[kk];
      acc0[1] = __builtin_amdgcn_mfma_f32_16x16x32_bf16(a0, b1, acc0[1], 0, 0, 0);
      acc1[1] = __builtin_amdgcn_mfma_f32_16x16x32_bf16(a1, b1, acc1[1], 0, 0, 0);
      short8 b2 = rb2[kk];
      acc0[2] = __builtin_amdgcn_mfma_f32_16x16x32_bf16(a0, b2, acc0[2], 0, 0, 0);
      acc1[2] = __builtin_amdgcn_mfma_f32_16x16x32_bf16(a1, b2, acc1[2], 0, 0, 0);
    }

    // c_up capture (all from PREVIOUS step's cp, before any update):
    float t00 = __shfl_up(cp0[3], 16);
    float t10 = __shfl_up(cp1[3], 16);
    float c15 = __shfl(cp0[3], 48 + col);           // row-15 c -> half1 quad0, same col
    float cu0[4], cu1[4];
    cu0[0] = quad ? t00 : 0.0f; cu0[1] = cp0[0]; cu0[2] = cp0[1]; cu0[3] = cp0[2];
    cu1[0] = quad ? t10 : c15;  cu1[1] = cp1[0]; cu1[2] = cp1[1]; cu1[3] = cp1[2];

    auto halfc = [&](float4v (&acc)[5], float (&cp)[4], float (&cu)[4], int mbase) {
#pragma unroll
      for (int r = 0; r < 4; ++r) {
        const int m = mbase + r;
        const int w = d - m;
        if (ALLV || (unsigned)w < 256u) {
          const float x = Xb[w * 32 + m];
          float zi = clamp15(fmaf(x, wx[0], acc[0][r]));
          float zg = clamp15(fmaf(x, wx[1], acc[1][r]));
          float z1 = clamp15(fmaf(x, wx[2], acc[2][r]));
          float z2 = clamp15(fmaf(x, wx[3], acc[3][r]));
          float zo = clamp15(fmaf(x, wx[4], acc[4][r]));
          float e1 = __expf(z1), e2 = __expf(z2), ei = __expf(zi), eg = __expf(2.0f * zg);
          float A1 = 1.0f + e1, A2 = 1.0f + e2, Ai = 1.0f + ei, G = 1.0f + eg;
          float P = Ai * G, Q = A1 * A2;
          float rD = fastrcp(P * Q);
          float c = (e1 * cp[r] * (A2 * P) + e2 * cu[r] * (A1 * P) + ei * (eg - 1.0f) * Q) * rD;
          float eo = __expf(-zo);
          float ec = __expf(2.0f * clamp15(c));
          float h = (ec - 1.0f) * fastrcp((1.0f + eo) * (ec + 1.0f));
          cp[r] = c;
          h_buf[wbuf][1 + m][jj] = f2bf(h);
          int s = sb - m; if (s < 0) s += 33;       // (d - m) mod 33
          featbuf[s][jj] += h;                      // unique (slot,jj) writer per step
        }
      }
    };
    halfc(acc0, cp0, cu0, quad * 4);
    halfc(acc1, cp1, cu1, 16 + quad * 4);
    __syncthreads();
  };

  BC<true> Tv; BC<false> Fv;
  for (int d = 0; d < 31; ++d)    { stepT(d, Fv); sb = (sb == 32) ? 0 : sb + 1; }
  for (int d = 31; d < 256; ++d)  { stepT(d, Tv); sb = (sb == 32) ? 0 : sb + 1; }
  for (int d = 256; d < 287; ++d) { stepT(d, Fv); sb = (sb == 32) ? 0 : sb + 1; }

  // Final column w=255 (complete after step 286; barrier at loop end).
  int fs = sb + 1; if (fs >= 33) fs = 0;            // sb=287%33=23 -> fs=24=255%33
  if (tid < 128) fb[255 * 128 + tid] = featbuf[fs][tid];
}

// ---------------------------------------------------------------------------
// logits = feat @ W_fc + b_fc, then log_softmax -> logp [32][256][101]
__global__ __launch_bounds__(256)
void logits_kernel(const float* __restrict__ feat, const float* __restrict__ Wfc,
                   const float* __restrict__ bfc, float* __restrict__ logp) {
  __shared__ float sW[128 * 101];
  __shared__ float sF[8][128];
  __shared__ float sL[8][104];
  __shared__ float sLse[8];
  const int tid = threadIdx.x;
  const int b  = blockIdx.x >> 5;
  const int t0 = (blockIdx.x & 31) * 8;

  for (int i = tid; i < 128 * 101; i += 256) sW[i] = Wfc[i];
  for (int i = tid; i < 8 * 128; i += 256)
    sF[i >> 7][i & 127] = feat[(b * 256 + t0 + (i >> 7)) * 128 + (i & 127)];
  __syncthreads();
  for (int idx = tid; idx < 8 * 101; idx += 256) {
    int tr = idx / 101, v = idx - tr * 101;
    float s = bfc[v];
#pragma unroll 4
    for (int k = 0; k < 128; ++k) s += sF[tr][k] * sW[k * 101 + v];
    sL[tr][v] = s;
  }
  __syncthreads();
  if (tid < 8) {
    float m = NEGF;
    for (int v = 0; v < 101; ++v) m = fmaxf(m, sL[tid][v]);
    float su = 0.0f;
    for (int v = 0; v < 101; ++v) su += __expf(sL[tid][v] - m);
    sLse[tid] = m + __logf(su);
  }
  __syncthreads();
  for (int idx = tid; idx < 8 * 101; idx += 256) {
    int tr = idx / 101, v = idx - tr * 101;
    logp[(b * 256 + t0 + tr) * 101 + v] = sL[tr][v] - sLse[tr];
  }
}

// ---------------------------------------------------------------------------
// CTC forward: one wave per batch. Lane l holds alpha[s=l]; lane 63 also s=64.
__global__ __launch_bounds__(64)
void ctc_kernel(const float* __restrict__ logp, const int* __restrict__ y,
                float* __restrict__ out) {
  const int b = blockIdx.x;
  const int l = threadIdx.x;
  const float* lpb = logp + b * 256 * 101;
  const int* yb = y + b * 32;
  int lab = (l & 1) ? yb[l >> 1] : 100;                 // ext[s]: odd->label, even->blank
  bool skip = (l & 1) && (l >= 3) && (yb[l >> 1] != yb[(l >> 1) - 1]);

  float a   = (l == 0) ? lpb[100] : ((l == 1) ? lpb[lab] : NEGF);
  float a64 = NEGF;                                      // alpha[64] (valid on lane 63)
  float pl[4], pb[4];
#pragma unroll
  for (int tt = 0; tt < 4; ++tt) {
    pl[tt] = lpb[(1 + tt) * 101 + lab];
    pb[tt] = lpb[(1 + tt) * 101 + 100];
  }
#pragma unroll 4
  for (int t = 1; t < 256; ++t) {
    const int s = (t - 1) & 3;
    float lpl = pl[s], lpbk = pb[s];
    if (t + 4 < 256) {                                   // refill slot with t+4
      pl[s] = lpb[(t + 4) * 101 + lab];
      pb[s] = lpb[(t + 4) * 101 + 100];
    }
    float am1 = __shfl_up(a, 1); if (l == 0) am1 = NEGF;
    float am2 = __shfl_up(a, 2); if (l < 2 || !skip) am2 = NEGF;
    float m3 = fmaxf(a, fmaxf(am1, am2));
    float na = m3 + __logf(__expf(a - m3) + __expf(am1 - m3) + __expf(am2 - m3)) + lpl;
    float m2 = fmaxf(a64, a);                            // s=64: lse(alpha64, alpha63)
    float na64 = m2 + __logf(__expf(a64 - m2) + __expf(a - m2)) + lpbk;
    a = na;
    a64 = na64;
  }
  float A63 = __shfl(a, 63);
  float A64 = __shfl(a64, 63);
  if (l == 0) {
    float m = fmaxf(A63, A64);
    out[b] = -(m + __logf(__expf(A63 - m) + __expf(A64 - m)));
  }
}

// ---------------------------------------------------------------------------
extern "C" void kernel_launch(void* const* d_in, const int* in_sizes, int n_in,
                              void* d_out, int out_size, void* d_ws, size_t ws_size,
                              hipStream_t stream) {
  const float* X   = (const float*)d_in[0];
  const int*   y   = (const int*)d_in[1];
  const float* Wx  = (const float*)d_in[2];
  const float* Wh1 = (const float*)d_in[3];
  const float* Wh2 = (const float*)d_in[4];
  const float* bi  = (const float*)d_in[5];
  const float* Wfc = (const float*)d_in[6];
  const float* bfc = (const float*)d_in[7];
  float* out = (float*)d_out;

  char* ws = (char*)d_ws;
  // Layout (max 0x778000 = 7.83 MB, same proven footprint):
  //   wsW   0x000000 - 0x050000  (bf16 weight frags)
  //   logp  0x050000 - 0x378000  (written by logits)
  //   feat  0x378000 - 0x778000  (4 MB, plain stores from LDS ring flush)
  short* wsW  = (short*)(ws);
  float* logp = (float*)(ws + 0x50000);
  float* feat = (float*)(ws + 0x378000);

  hipMemsetAsync(feat, 0, 32 * 256 * 128 * sizeof(float), stream);
  prep_w_kernel<<<80, 256, 0, stream>>>(Wh1, Wh2, wsW);
  mdlstm_kernel<<<32, 512, 0, stream>>>(X, wsW, Wx, bi, feat);
  logits_kernel<<<1024, 256, 0, stream>>>(feat, Wfc, bfc, logp);
  ctc_kernel<<<32, 64, 0, stream>>>(logp, y, out);
}

// Round 3
// 866.318 us; speedup vs baseline: 1.2462x; 1.2462x over previous
//
#include <hip/hip_runtime.h>

#define NEGF (-1e30f)

typedef __attribute__((ext_vector_type(8))) short short8;
typedef __attribute__((ext_vector_type(4))) float float4v;

template <bool V> struct BC { static constexpr bool value = V; };

__device__ __forceinline__ short f2bf(float f) {
  union { float f; unsigned u; } v; v.f = f;
  unsigned r = v.u + 0x7fffu + ((v.u >> 16) & 1u);  // RNE truncate to bf16
  return (short)(r >> 16);
}
__device__ __forceinline__ float fastrcp(float x) { return __builtin_amdgcn_rcpf(x); }
__device__ __forceinline__ float clamp15(float x) { return fminf(15.0f, fmaxf(-15.0f, x)); }

// ---------------------------------------------------------------------------
// prep: stage Wcat = [Wh1;Wh2] (256x640 f32) into bf16 MFMA B-fragment layout.
__global__ void prep_w_kernel(const float* __restrict__ Wh1, const float* __restrict__ Wh2,
                              short* __restrict__ wsW) {
  int t = blockIdx.x * 256 + threadIdx.x;   // 0..20479
  int lane = t & 63;
  int frag = t >> 6;                        // 0..319
  int nt = frag >> 3, kk = frag & 7;
  int n  = nt * 16 + (lane & 15);
  int kb = kk * 32 + (lane >> 4) * 8;
  short8 v;
#pragma unroll
  for (int j = 0; j < 8; ++j) {
    int k = kb + j;
    float w = (k < 128) ? Wh1[k * 640 + n] : Wh2[(k - 128) * 640 + n];
    v[j] = f2bf(w);
  }
  ((short8*)wsW)[frag * 64 + lane] = v;
}

// ---------------------------------------------------------------------------
// MDLSTM wavefront, TWO CUs per batch (64 blocks): A rows 0-15, B rows 16-31.
// vs R0 (877us proven): same step math, new sync protocol:
//  - flag spins amortized 8x (B tracks knownA, spins for fA >= e+8 once per
//    8 steps; A updates fA / checks ring credit every 8 steps). Barrier-drain
//    before each flag update preserves publish->flag ordering.
//  - boundary prefetched one step early (atomic read RT hides under compute).
//  - feat: per-half 17-slot LDS ring, one atomicAdd per column per thread
//    (128/step instead of 2048/step per block).
// Deadlock-free: A free when B >= d-15, B free when A >= e+15 (disjoint).
__global__ __launch_bounds__(512)
void mdlstm_kernel(const float* __restrict__ X, const short* __restrict__ wsW,
                   const float* __restrict__ Wx, const float* __restrict__ bias,
                   float* __restrict__ feat, float* __restrict__ bH0,
                   float* __restrict__ bC0, int* __restrict__ flagA,
                   int* __restrict__ flagB) {
  __shared__ __align__(16) short h_buf[2][17][136];   // 9,248 B
  __shared__ __align__(16) short wlds[128 * 512];     // 131,072 B: gates 3,4
  __shared__ float featbuf[17][132];                  // 8,976 B: column ring
  // LDS total 149,296 B (< proven 156,704)

  const int blk  = blockIdx.x;
  const int bat  = blk >> 1;
  const bool isB = blk & 1;
  const int tid  = threadIdx.x;
  const int lane = tid & 63;
  const int g    = tid >> 6;
  const int col  = lane & 15;
  const int quad = lane >> 4;
  const int jj   = g * 16 + col;

  for (int i = tid; i < 2 * 17 * 136 / 2; i += 512) ((int*)h_buf)[i] = 0;
  for (int i = tid; i < 17 * 132; i += 512) ((float*)featbuf)[i] = 0.0f;
  {
    const uint4* src = (const uint4*)(wsW + 192 * 512);  // frags 192.. (q=3,4)
    uint4* dst = (uint4*)wlds;
    for (int i = tid; i < 8192; i += 512) dst[i] = src[i];
  }

  float wx[5], bg[5];
#pragma unroll
  for (int q = 0; q < 5; ++q) {
    wx[q] = Wx[q * 128 + jj];
    bg[q] = bias[q * 128 + jj];
  }
  float cp[4] = {0.f, 0.f, 0.f, 0.f};   // c-state: rows mbase..mbase+3
  float c15 = 0.0f;                      // B only, valid on quad0 lanes
  float pre_h = 0.0f, pre_c = 0.0f;      // B prefetch registers
  int knownA = 0;                        // lane0-valid: last spun fA value

  const float* Xg = X + bat * 8192;
  float* fb = feat + bat * 32768;
  float* bH = bH0 + bat * 32 * 128;
  float* bC = bC0 + bat * 32 * 128;
  int* fA = flagA + bat;
  int* fB = flagB + bat;
  const short8* W8 = (const short8*)wsW;
  const short8* pW0 = W8 + ((0 * 8 + g) * 8) * 64 + lane;
  const short8* pW1 = W8 + ((1 * 8 + g) * 8) * 64 + lane;
  const short8* pW2 = W8 + ((2 * 8 + g) * 8) * 64 + lane;
  const short8* pL3 = (const short8*)&wlds[((0 * 8 + g) * 8) * 512 + lane * 8];
  const short8* pL4 = (const short8*)&wlds[((1 * 8 + g) * 8) * 512 + lane * 8];
  const int mbase = (isB ? 16 : 0) + quad * 4;           // global row of r=0
  const int widx0 = (isB ? 1 : 0) + quad * 4;            // LDS row of r=0
  const float* pX = Xg - 31 * mbase;                     // + d*32 per diag
  int sb = 0;                                            // A: d%17, B: (d-16)%17
  __syncthreads();

  auto step = [&](int d, auto isb_, auto allv_) {
    constexpr bool IsB = decltype(isb_)::value;
    constexpr bool ALLV = decltype(allv_)::value;
    const int rbuf = (d + 1) & 1, wbuf = d & 1;

    // Flush completed column w (A: d-16, B: d-32). Slot (sb+1)%17 is written
    // by NO ring-writer during step d (they cover the other 16 slots), and the
    // value was complete at end of step d-1 (barrier-separated).
    const int wfl = d - (IsB ? 32 : 16);
    if (wfl >= 0 && tid < 128) {
      int fs = sb + 1; if (fs >= 17) fs = 0;
      float v = featbuf[fs][tid];
      featbuf[fs][tid] = 0.0f;
      atomicAdd(&fb[wfl * 128 + tid], v);                // once per column, not per cell
    }

    float4v acc[5];
#pragma unroll
    for (int q = 0; q < 5; ++q) acc[q] = (float4v){bg[q], bg[q], bg[q], bg[q]};
    const short8 z8 = (short8){0, 0, 0, 0, 0, 0, 0, 0};
#pragma unroll
    for (int kk = 0; kk < 8; ++kk) {
      const int up = (kk >= 4) ? 1 : 0;                  // kk<4: h_left; else h_up
      const int cc = (kk & 3) * 32 + quad * 8;
      int row = col + (IsB ? 1 : 0) - up;
      short8 a0 = (IsB || row >= 0) ? *(const short8*)&h_buf[rbuf][row][cc] : z8;
      short8 b3 = pL3[kk * 64];
      acc[3] = __builtin_amdgcn_mfma_f32_16x16x32_bf16(a0, b3, acc[3], 0, 0, 0);
      short8 b4 = pL4[kk * 64];
      acc[4] = __builtin_amdgcn_mfma_f32_16x16x32_bf16(a0, b4, acc[4], 0, 0, 0);
      short8 b2 = pW2[kk * 64];
      acc[2] = __builtin_amdgcn_mfma_f32_16x16x32_bf16(a0, b2, acc[2], 0, 0, 0);
      short8 b0 = pW0[kk * 64];
      acc[0] = __builtin_amdgcn_mfma_f32_16x16x32_bf16(a0, b0, acc[0], 0, 0, 0);
      short8 b1 = pW1[kk * 64];
      acc[1] = __builtin_amdgcn_mfma_f32_16x16x32_bf16(a0, b1, acc[1], 0, 0, 0);
    }

    float t0 = __shfl_up(cp[3], 16);
    float cu[4];
    cu[0] = quad ? t0 : (IsB ? c15 : 0.0f);
    cu[1] = cp[0]; cu[2] = cp[1]; cu[3] = cp[2];
    const float* pXd = pX + d * 32;
    float xm[4];
#pragma unroll
    for (int r = 0; r < 4; ++r) {
      int w = d - (mbase + r);
      if (ALLV || (w >= 0 && w < 256)) xm[r] = pXd[-31 * r];
    }
#pragma unroll
    for (int r = 0; r < 4; ++r) {
      const int w = d - (mbase + r);
      if (ALLV || (w >= 0 && w < 256)) {
        float c_up = cu[r];
        float c_l  = cp[r];
        float x    = xm[r];
        float zi = clamp15(fmaf(x, wx[0], acc[0][r]));
        float zg = clamp15(fmaf(x, wx[1], acc[1][r]));
        float z1 = clamp15(fmaf(x, wx[2], acc[2][r]));
        float z2 = clamp15(fmaf(x, wx[3], acc[3][r]));
        float zo = clamp15(fmaf(x, wx[4], acc[4][r]));
        float e1 = __expf(z1), e2 = __expf(z2), ei = __expf(zi), eg = __expf(2.0f * zg);
        float A1 = 1.0f + e1, A2 = 1.0f + e2, Ai = 1.0f + ei, G = 1.0f + eg;
        float P = Ai * G, Q = A1 * A2;
        float rD = fastrcp(P * Q);
        float c = (e1 * c_l * (A2 * P) + e2 * c_up * (A1 * P) + ei * (eg - 1.0f) * Q) * rD;
        float eo = __expf(-zo);
        float ec = __expf(2.0f * clamp15(c));
        float h = (ec - 1.0f) * fastrcp((1.0f + eo) * (ec + 1.0f));
        cp[r] = c;
        h_buf[wbuf][widx0 + r][jj] = f2bf(h);
        int s = sb - (quad * 4 + r); if (s < 0) s += 17; // slot = w mod 17
        featbuf[s][jj] += h;                             // unique (slot,jj) writer
        if (!IsB && r == 3 && quad == 3 && d >= 15) {    // publish row-15 boundary
          const int slot = (d & 31) * 128 + jj;
          atomicExch(&bH[slot], h);
          atomicExch(&bC[slot], c);
        }
      }
    }
  };

  BC<true> Tv; BC<false> Fv;
  if (!isB) {
    auto aiter = [&](int d, auto allv) {
      if (d >= 48 && (d & 7) == 0 && lane == 0) {        // ring credit, 1/8 steps
        while (atomicAdd(fB, 0) < d - 22) {}
      }
      step(d, Fv, allv);
      sb = (sb == 16) ? 0 : sb + 1;
      __syncthreads();                                   // drains publishes (vmcnt 0)
      if ((((d + 1) & 7) == 0 || d == 270) && tid == 0) atomicExch(fA, d + 1);
    };
    for (int d = 0; d < 15; ++d)    aiter(d, Fv);
    for (int d = 15; d < 256; ++d)  aiter(d, Tv);
    for (int d = 256; d < 271; ++d) aiter(d, Fv);
    if (tid < 128) atomicAdd(&fb[255 * 128 + tid], featbuf[0][tid]);  // w=255 (slot 255%17=0)
  } else {
    {                                                    // initial prefetch: slot 15 for e=16
      if (lane == 0) { while (atomicAdd(fA, 0) < 23) {} knownA = 23; }
      const int slot = 15 * 128 + jj;
      if (quad == 1) pre_h = atomicAdd(&bH[slot], 0.0f);
      else if (quad == 0) pre_c = atomicAdd(&bC[slot], 0.0f);
    }
    auto biter = [&](int e, auto allv) {
      // commit boundary bnd[e-1] (prefetched last iter; RT already hidden)
      if (quad == 1) h_buf[(e + 1) & 1][0][jj] = f2bf(pre_h);
      else if (quad == 0) c15 = pre_c;
      // prefetch slot e for step e+1; spin only 1/8 steps
      const int ee = e + 1;
      if (ee <= 271) {
        if (lane == 0 && knownA < ee) {
          int tgt = ee + 7; if (tgt > 271) tgt = 271;
          while (atomicAdd(fA, 0) < tgt) {}
          knownA = tgt;
        }
        const int slot = ((ee - 1) & 31) * 128 + jj;
        if (quad == 1) pre_h = atomicAdd(&bH[slot], 0.0f);
        else if (quad == 0) pre_c = atomicAdd(&bC[slot], 0.0f);
      } else {
        pre_h = 0.0f; pre_c = 0.0f;                      // beyond A's range -> zeros
      }
      __syncthreads();                                   // row0 commit visible to all
      step(e, Tv, allv);
      sb = (sb == 16) ? 0 : sb + 1;
      if (((e & 7) == 7 || e == 286) && tid == 0) atomicExch(fB, e);
    };
    for (int e = 16; e < 31; ++e)   biter(e, Fv);
    for (int e = 31; e < 272; ++e)  biter(e, Tv);
    for (int e = 272; e < 287; ++e) biter(e, Fv);
    __syncthreads();                                     // last step's ring writes
    if (tid < 128) atomicAdd(&fb[255 * 128 + tid], featbuf[0][tid]);
  }
}

// ---------------------------------------------------------------------------
// logits = feat @ W_fc + b_fc, then log_softmax -> logp [32][256][101]
__global__ __launch_bounds__(256)
void logits_kernel(const float* __restrict__ feat, const float* __restrict__ Wfc,
                   const float* __restrict__ bfc, float* __restrict__ logp) {
  __shared__ float sW[128 * 101];
  __shared__ float sF[8][128];
  __shared__ float sL[8][104];
  __shared__ float sLse[8];
  const int tid = threadIdx.x;
  const int b  = blockIdx.x >> 5;
  const int t0 = (blockIdx.x & 31) * 8;

  for (int i = tid; i < 128 * 101; i += 256) sW[i] = Wfc[i];
  for (int i = tid; i < 8 * 128; i += 256)
    sF[i >> 7][i & 127] = feat[(b * 256 + t0 + (i >> 7)) * 128 + (i & 127)];
  __syncthreads();
  for (int idx = tid; idx < 8 * 101; idx += 256) {
    int tr = idx / 101, v = idx - tr * 101;
    float s = bfc[v];
#pragma unroll 4
    for (int k = 0; k < 128; ++k) s += sF[tr][k] * sW[k * 101 + v];
    sL[tr][v] = s;
  }
  __syncthreads();
  if (tid < 8) {
    float m = NEGF;
    for (int v = 0; v < 101; ++v) m = fmaxf(m, sL[tid][v]);
    float su = 0.0f;
    for (int v = 0; v < 101; ++v) su += __expf(sL[tid][v] - m);
    sLse[tid] = m + __logf(su);
  }
  __syncthreads();
  for (int idx = tid; idx < 8 * 101; idx += 256) {
    int tr = idx / 101, v = idx - tr * 101;
    logp[(b * 256 + t0 + tr) * 101 + v] = sL[tr][v] - sLse[tr];
  }
}

// ---------------------------------------------------------------------------
// CTC forward: one wave per batch. Lane l holds alpha[s=l]; lane 63 also s=64.
__global__ __launch_bounds__(64)
void ctc_kernel(const float* __restrict__ logp, const int* __restrict__ y,
                float* __restrict__ out) {
  const int b = blockIdx.x;
  const int l = threadIdx.x;
  const float* lpb = logp + b * 256 * 101;
  const int* yb = y + b * 32;
  int lab = (l & 1) ? yb[l >> 1] : 100;                 // ext[s]: odd->label, even->blank
  bool skip = (l & 1) && (l >= 3) && (yb[l >> 1] != yb[(l >> 1) - 1]);

  float a   = (l == 0) ? lpb[100] : ((l == 1) ? lpb[lab] : NEGF);
  float a64 = NEGF;                                      // alpha[64] (valid on lane 63)
  float pl[4], pb[4];
#pragma unroll
  for (int tt = 0; tt < 4; ++tt) {
    pl[tt] = lpb[(1 + tt) * 101 + lab];
    pb[tt] = lpb[(1 + tt) * 101 + 100];
  }
#pragma unroll 4
  for (int t = 1; t < 256; ++t) {
    const int s = (t - 1) & 3;
    float lpl = pl[s], lpbk = pb[s];
    if (t + 4 < 256) {                                   // refill slot with t+4
      pl[s] = lpb[(t + 4) * 101 + lab];
      pb[s] = lpb[(t + 4) * 101 + 100];
    }
    float am1 = __shfl_up(a, 1); if (l == 0) am1 = NEGF;
    float am2 = __shfl_up(a, 2); if (l < 2 || !skip) am2 = NEGF;
    float m3 = fmaxf(a, fmaxf(am1, am2));
    float na = m3 + __logf(__expf(a - m3) + __expf(am1 - m3) + __expf(am2 - m3)) + lpl;
    float m2 = fmaxf(a64, a);                            // s=64: lse(alpha64, alpha63)
    float na64 = m2 + __logf(__expf(a64 - m2) + __expf(a - m2)) + lpbk;
    a = na;
    a64 = na64;
  }
  float A63 = __shfl(a, 63);
  float A64 = __shfl(a64, 63);
  if (l == 0) {
    float m = fmaxf(A63, A64);
    out[b] = -(m + __logf(__expf(A63 - m) + __expf(A64 - m)));
  }
}

// ---------------------------------------------------------------------------
extern "C" void kernel_launch(void* const* d_in, const int* in_sizes, int n_in,
                              void* d_out, int out_size, void* d_ws, size_t ws_size,
                              hipStream_t stream) {
  const float* X   = (const float*)d_in[0];
  const int*   y   = (const int*)d_in[1];
  const float* Wx  = (const float*)d_in[2];
  const float* Wh1 = (const float*)d_in[3];
  const float* Wh2 = (const float*)d_in[4];
  const float* bi  = (const float*)d_in[5];
  const float* Wfc = (const float*)d_in[6];
  const float* bfc = (const float*)d_in[7];
  float* out = (float*)d_out;

  char* ws = (char*)d_ws;
  // Layout (max 0x778000 = 7.83 MB, proven footprint):
  //   wsW   0x000000 - 0x050000  (bf16 weight frags)
  //   bndH  0x050000 - 0x0D0000  (32 batches x 32-slot ring x 128 f32)   } dead after
  //   bndC  0x0D0000 - 0x150000                                          } mdlstm ->
  //   flags 0x150000 - 0x151000                                          } overlaid
  //   logp  0x050000 - 0x378000  (written by logits, after mdlstm)       } by logp
  //   feat  0x378000 - 0x778000  (4 MB, column-flush atomicAdd)
  short* wsW  = (short*)(ws);
  float* bndH = (float*)(ws + 0x50000);
  float* bndC = (float*)(ws + 0xD0000);
  int*   flgA = (int*)(ws + 0x150000);
  int*   flgB = (int*)(ws + 0x150800);
  float* logp = (float*)(ws + 0x50000);
  float* feat = (float*)(ws + 0x378000);

  hipMemsetAsync(feat, 0, 32 * 256 * 128 * sizeof(float), stream);  // ring flush accumulates onto 0
  prep_w_kernel<<<80, 256, 0, stream>>>(Wh1, Wh2, wsW);
  mdlstm_kernel<<<64, 512, 0, stream>>>(X, wsW, Wx, bi, feat, bndH, bndC, flgA, flgB);
  logits_kernel<<<1024, 256, 0, stream>>>(feat, Wfc, bfc, logp);
  ctc_kernel<<<32, 64, 0, stream>>>(logp, y, out);
}